// Round 3
// baseline (457.954 us; speedup 1.0000x reference)
//
#include <hip/hip_runtime.h>

#define VOCAB 50000
#define SEQ   200

// ---------------------------------------------------------------------------
// Kernel 1: dense zero fill of the whole [batch, VOCAB] f32 output.
// Structured like the runtime's fillBufferAligned (which measures 5.8+ TB/s
// on this chip at ~10% occupancy): pure grid-stride dwordx4 stores of a
// register, no LDS, no barrier, no atomic tail. Nothing chops the store
// stream into bursts.
// ---------------------------------------------------------------------------
__global__ __launch_bounds__(256) void MultihotEmbedding_zero_kernel(
    float4* __restrict__ o4, int n4) {
  const int stride = gridDim.x * 256;
  const float4 z = make_float4(0.f, 0.f, 0.f, 0.f);
  for (int i = blockIdx.x * 256 + threadIdx.x; i < n4; i += stride) o4[i] = z;
}

// ---------------------------------------------------------------------------
// Kernel 2: sparse scatter of the 409600 token increments. One thread per
// token (gid-coalesced x reads), one global f32 atomicAdd each. Duplicate
// indices within a row combine exactly (counts <= 200, integers exact in
// f32). Runs after the zero kernel on the same stream; the dispatch-boundary
// release/acquire makes the zeros visible across XCDs.
// ---------------------------------------------------------------------------
__global__ __launch_bounds__(256) void MultihotEmbedding_scatter_kernel(
    const int* __restrict__ x, float* __restrict__ out, int ntok) {
  const int gid = blockIdx.x * 256 + threadIdx.x;
  if (gid < ntok) {
    const int row = gid / SEQ;            // compiler magic-mul, ~3 VALU ops
    const int idx = x[gid];
    atomicAdd(out + (size_t)row * VOCAB + idx, 1.0f);
  }
}

extern "C" void kernel_launch(void* const* d_in, const int* in_sizes, int n_in,
                              void* d_out, int out_size, void* d_ws, size_t ws_size,
                              hipStream_t stream) {
  const int* x = (const int*)d_in[0];
  float* out = (float*)d_out;
  const int batch = in_sizes[0] / SEQ;        // 2048
  const int ntok = batch * SEQ;               // 409600
  const int n4 = batch * (VOCAB / 4);         // 25,600,000 float4 (divisible)

  // Phase 1: pure write stream, 2048 blocks (8/CU), ~49 float4 per thread.
  MultihotEmbedding_zero_kernel<<<2048, 256, 0, stream>>>((float4*)out, n4);

  // Phase 2: one atomic per token, 1600 blocks x 256 threads.
  MultihotEmbedding_scatter_kernel<<<(ntok + 255) / 256, 256, 0, stream>>>(
      x, out, ntok);
}